// Round 1
// baseline (1322.345 us; speedup 1.0000x reference)
//
#include <hip/hip_runtime.h>
#include <math.h>

// Problem constants (fixed by reference setup_inputs)
#define NROWS 8192
#define DDIM  256
#define INV_TEMP 1.25f      // 1/0.8
#define EPS_V 1e-7f
#define NORM_EPS 1e-12f

// Tiling
#define BI 64
#define BJ 64
#define BK 64
#define PADK 68            // keep 16B alignment for float4 LDS reads; stride 68 words -> <=2-way bank alias (free)
#define SPLITJ 16          // j-range splits per i-tile; grid = 128 x 16 = 2048 blocks

// ---------------- workspace layout (floats) ----------------
// [0      .. 8191 ] inv_norm
// [8192   .. 16383] num
// [16384  .. 24575] den

__global__ void zero_kernel(float* __restrict__ ws) {
    int i = blockIdx.x * blockDim.x + threadIdx.x;
    if (i < 2 * NROWS) ws[NROWS + i] = 0.0f;
}

// One wave per row: 64 lanes x float4 = 256 floats, shuffle-reduce sum of squares.
__global__ void norm_kernel(const float* __restrict__ feat, float* __restrict__ inv_norm) {
    int row  = (blockIdx.x * blockDim.x + threadIdx.x) >> 6;
    int lane = threadIdx.x & 63;
    if (row >= NROWS) return;
    const float4 v = reinterpret_cast<const float4*>(feat + (size_t)row * DDIM)[lane];
    float s = v.x * v.x + v.y * v.y + v.z * v.z + v.w * v.w;
    #pragma unroll
    for (int m = 32; m > 0; m >>= 1) s += __shfl_xor(s, m);
    if (lane == 0) {
        float n = fmaxf(sqrtf(s), NORM_EPS);
        inv_norm[row] = 1.0f / n;
    }
}

// Fused normalize-GEMM-exp-mask-rowsum.
// Block computes C-tile rows [i0, i0+64) x cols [j_begin, j_begin+512), accumulating
// num/den per row in registers, one atomicAdd per row fragment at the end.
__global__ __launch_bounds__(256) void main_kernel(
        const float* __restrict__ feat,
        const int*   __restrict__ lab,
        const int*   __restrict__ spk,
        const float* __restrict__ inv_norm,
        float*       __restrict__ num,
        float*       __restrict__ den) {
    __shared__ float As[BI][PADK];
    __shared__ float Bs[BJ][PADK];

    const int i0      = blockIdx.x * BI;
    const int j_begin = blockIdx.y * (NROWS / SPLITJ);
    const int j_end   = j_begin + (NROWS / SPLITJ);

    const int tid = threadIdx.x;
    const int tx  = tid & 15;   // column group (4 cols each)
    const int ty  = tid >> 4;   // row group (4 rows each)

    int   li[4], si[4];
    float nacc[4] = {0.f, 0.f, 0.f, 0.f};
    float dacc[4] = {0.f, 0.f, 0.f, 0.f};
    #pragma unroll
    for (int r = 0; r < 4; ++r) {
        const int gi = i0 + ty * 4 + r;
        li[r] = lab[gi];
        si[r] = spk[gi];
    }

    for (int j0 = j_begin; j0 < j_end; j0 += BJ) {
        float acc[4][4];
        #pragma unroll
        for (int r = 0; r < 4; ++r)
            #pragma unroll
            for (int c = 0; c < 4; ++c) acc[r][c] = 0.0f;

        for (int kc = 0; kc < DDIM; kc += BK) {
            // Stage A and B tiles (64 rows x 64 k), normalizing on the fly.
            // 1024 float4s per tile; 256 threads x 4 each. Coalesced: consecutive
            // tids cover consecutive 16B chunks of a row.
            #pragma unroll
            for (int l = 0; l < 4; ++l) {
                const int idx = tid + l * 256;      // 0..1023
                const int row = idx >> 4;
                const int c4  = (idx & 15) * 4;
                const float inv_i = inv_norm[i0 + row];
                float4 va = *reinterpret_cast<const float4*>(
                    feat + (size_t)(i0 + row) * DDIM + kc + c4);
                As[row][c4 + 0] = va.x * inv_i;
                As[row][c4 + 1] = va.y * inv_i;
                As[row][c4 + 2] = va.z * inv_i;
                As[row][c4 + 3] = va.w * inv_i;
                const float inv_j = inv_norm[j0 + row];
                float4 vb = *reinterpret_cast<const float4*>(
                    feat + (size_t)(j0 + row) * DDIM + kc + c4);
                Bs[row][c4 + 0] = vb.x * inv_j;
                Bs[row][c4 + 1] = vb.y * inv_j;
                Bs[row][c4 + 2] = vb.z * inv_j;
                Bs[row][c4 + 3] = vb.w * inv_j;
            }
            __syncthreads();

            #pragma unroll
            for (int kk = 0; kk < BK; kk += 4) {
                float4 a[4], b[4];
                #pragma unroll
                for (int r = 0; r < 4; ++r)
                    a[r] = *reinterpret_cast<const float4*>(&As[ty * 4 + r][kk]);
                #pragma unroll
                for (int c = 0; c < 4; ++c)
                    b[c] = *reinterpret_cast<const float4*>(&Bs[tx * 4 + c][kk]);
                #pragma unroll
                for (int r = 0; r < 4; ++r)
                    #pragma unroll
                    for (int c = 0; c < 4; ++c)
                        acc[r][c] += a[r].x * b[c].x + a[r].y * b[c].y +
                                     a[r].z * b[c].z + a[r].w * b[c].w;
            }
            __syncthreads();
        }

        // Epilogue: exp + masks, accumulate per-row num/den (registers only).
        int lj[4], sj[4];
        #pragma unroll
        for (int c = 0; c < 4; ++c) {
            const int gj = j0 + tx * 4 + c;
            lj[c] = lab[gj];
            sj[c] = spk[gj];
        }
        #pragma unroll
        for (int r = 0; r < 4; ++r) {
            const int gi = i0 + ty * 4 + r;
            #pragma unroll
            for (int c = 0; c < 4; ++c) {
                const int gj = j0 + tx * 4 + c;
                const float e = __expf(acc[r][c] * INV_TEMP);
                const bool same_lab = (li[r] == lj[c]) && (gi != gj);
                const bool same_spk = (si[r] == sj[c]);
                nacc[r] += (same_lab && same_spk)  ? e : 0.0f;
                dacc[r] += (same_lab && !same_spk) ? e : 0.0f;
            }
        }
    }

    // Reduce across the 16 tx threads (they sit in consecutive lanes).
    #pragma unroll
    for (int r = 0; r < 4; ++r) {
        #pragma unroll
        for (int m = 1; m < 16; m <<= 1) {
            nacc[r] += __shfl_xor(nacc[r], m);
            dacc[r] += __shfl_xor(dacc[r], m);
        }
    }
    if (tx == 0) {
        #pragma unroll
        for (int r = 0; r < 4; ++r) {
            const int gi = i0 + ty * 4 + r;
            atomicAdd(&num[gi], nacc[r]);
            atomicAdd(&den[gi], dacc[r]);
        }
    }
}

__global__ void final_kernel(const float* __restrict__ num,
                             const float* __restrict__ den,
                             float* __restrict__ out) {
    __shared__ float s_tot[256];
    __shared__ int   s_cnt[256];
    float tot = 0.0f;
    int   cnt = 0;
    for (int i = threadIdx.x; i < NROWS; i += 256) {
        const float n = num[i];
        if (n > 0.0f) {               // valid <=> some positive exists (exp > 0)
            const float d = den[i] + n + EPS_V;
            tot += logf(d) - logf(n);
            cnt += 1;
        }
    }
    s_tot[threadIdx.x] = tot;
    s_cnt[threadIdx.x] = cnt;
    __syncthreads();
    for (int s = 128; s > 0; s >>= 1) {
        if (threadIdx.x < s) {
            s_tot[threadIdx.x] += s_tot[threadIdx.x + s];
            s_cnt[threadIdx.x] += s_cnt[threadIdx.x + s];
        }
        __syncthreads();
    }
    if (threadIdx.x == 0)
        out[0] = (s_cnt[0] > 0) ? (s_tot[0] / (float)s_cnt[0]) : 0.0f;
}

extern "C" void kernel_launch(void* const* d_in, const int* in_sizes, int n_in,
                              void* d_out, int out_size, void* d_ws, size_t ws_size,
                              hipStream_t stream) {
    const float* feat = (const float*)d_in[0];
    const int*   lab  = (const int*)d_in[1];
    const int*   spk  = (const int*)d_in[2];
    float* ws       = (float*)d_ws;
    float* inv_norm = ws;
    float* num      = ws + NROWS;
    float* den      = ws + 2 * NROWS;
    float* out      = (float*)d_out;

    zero_kernel<<<(2 * NROWS + 255) / 256, 256, 0, stream>>>(ws);
    norm_kernel<<<(NROWS * 64 + 255) / 256, 256, 0, stream>>>(feat, inv_norm);
    dim3 grid(NROWS / BI, SPLITJ);
    main_kernel<<<grid, 256, 0, stream>>>(feat, lab, spk, inv_norm, num, den);
    final_kernel<<<1, 256, 0, stream>>>(num, den, out);
}

// Round 2
// 200.742 us; speedup vs baseline: 6.5873x; 6.5873x over previous
//
#include <hip/hip_runtime.h>
#include <math.h>

// Problem constants (fixed by reference setup_inputs)
#define NROWS 8192
#define DDIM  256
#define INV_TEMP 1.25f      // 1/0.8
#define EPS_V 1e-7f

// Tiling
#define BI 128
#define BJ 128
#define BK 64
#define JSPLIT 16           // each block covers 8192/16 = 512 cols = 4 j-tiles of 128

typedef float f32x4 __attribute__((ext_vector_type(4)));
typedef short s16x8 __attribute__((ext_vector_type(8)));

// ---------------- workspace layout ----------------
// [0           .. 4MB )  fbf : normalized features as bf16 (ushort), row-major 8192x256
// [4MB         .. +32KB)  num : 8192 f32
// [ +32KB      .. +64KB)  den : 8192 f32

__device__ __forceinline__ ushort f2bf(float x) {
    // round-to-nearest-even fp32 -> bf16 (inputs are finite, no NaN handling needed)
    unsigned u = __float_as_uint(x);
    unsigned r = (u + 0x7FFFu + ((u >> 16) & 1u)) >> 16;
    return (ushort)r;
}

__global__ void zero_kernel(float* __restrict__ p) {
    int i = blockIdx.x * 256 + threadIdx.x;
    if (i < 2 * NROWS) p[i] = 0.0f;
}

// One wave per row: 64 lanes x float4 = 256 floats. Normalize + convert to bf16.
__global__ void normbf_kernel(const float* __restrict__ feat, ushort* __restrict__ fbf) {
    const int row  = (blockIdx.x * blockDim.x + threadIdx.x) >> 6;
    const int lane = threadIdx.x & 63;
    const float4 v = reinterpret_cast<const float4*>(feat + (size_t)row * DDIM)[lane];
    float ss = v.x * v.x + v.y * v.y + v.z * v.z + v.w * v.w;
    #pragma unroll
    for (int m = 32; m; m >>= 1) ss += __shfl_xor(ss, m);
    const float inv = 1.0f / fmaxf(sqrtf(ss), 1e-12f);
    ushort4 o;
    o.x = f2bf(v.x * inv);
    o.y = f2bf(v.y * inv);
    o.z = f2bf(v.z * inv);
    o.w = f2bf(v.w * inv);
    reinterpret_cast<ushort4*>(fbf + (size_t)row * DDIM)[lane] = o;
}

// Fused bf16 MFMA GEMM (C = f . f^T / T) + exp + mask + per-row num/den accumulation.
// Block: 256 threads = 4 waves in 2x2, each wave owns a 64x64 quadrant of the
// 128x128 C-tile. LDS tiles are chunk-XOR-swizzled (p = c ^ (row&7)) so both
// ds_write_b128 and ds_read_b128 are <=2-way bank aliased (free).
__global__ __launch_bounds__(256) void main_kernel(
        const ushort* __restrict__ fbf,
        const int*    __restrict__ lab,
        const int*    __restrict__ spk,
        float*        __restrict__ num,
        float*        __restrict__ den) {
    __shared__ __align__(16) ushort As[BI * BK];   // 16 KB
    __shared__ __align__(16) ushort Bs[BJ * BK];   // 16 KB

    const int tid  = threadIdx.x;
    const int lane = tid & 63;
    const int wid  = tid >> 6;      // 0..3
    const int wr   = wid >> 1;      // wave row  (0..1)
    const int wc   = wid & 1;       // wave col  (0..1)
    const int g    = lane >> 4;     // 0..3
    const int ln   = lane & 15;

    const int i0   = blockIdx.x * BI;
    const int jbeg = blockIdx.y * (NROWS / JSPLIT);

    float nacc[16], dacc[16];       // per-thread: 16 rows (fi x reg), summed over cols
    #pragma unroll
    for (int t = 0; t < 16; ++t) { nacc[t] = 0.0f; dacc[t] = 0.0f; }

    for (int jt = 0; jt < (NROWS / JSPLIT) / BJ; ++jt) {   // 4 j-tiles
        const int j0 = jbeg + jt * BJ;

        f32x4 acc[4][4];
        #pragma unroll
        for (int fi = 0; fi < 4; ++fi)
            #pragma unroll
            for (int fj = 0; fj < 4; ++fj)
                #pragma unroll
                for (int k = 0; k < 4; ++k) acc[fi][fj][k] = 0.0f;

        for (int kc = 0; kc < DDIM; kc += BK) {
            // Stage A and B chunks: 128 rows x 64 bf16 each = 1024 x 16B chunks,
            // 256 threads x 4 chunks. XOR-swizzle the chunk slot within each row.
            #pragma unroll
            for (int l = 0; l < 4; ++l) {
                const int idx = tid + l * 256;     // 0..1023
                const int row = idx >> 3;
                const int c   = idx & 7;           // logical 16B chunk in row
                const int p   = c ^ (row & 7);     // physical slot
                const float4 va = *reinterpret_cast<const float4*>(
                    fbf + (size_t)(i0 + row) * DDIM + kc + c * 8);
                *reinterpret_cast<float4*>(&As[row * BK + p * 8]) = va;
                const float4 vb = *reinterpret_cast<const float4*>(
                    fbf + (size_t)(j0 + row) * DDIM + kc + c * 8);
                *reinterpret_cast<float4*>(&Bs[row * BK + p * 8]) = vb;
            }
            __syncthreads();

            #pragma unroll
            for (int ks = 0; ks < 2; ++ks) {       // two K=32 steps per BK=64
                s16x8 a[4], b[4];
                #pragma unroll
                for (int f = 0; f < 4; ++f) {
                    const int ra = wr * 64 + f * 16 + ln;
                    const int pa = (ks * 4 + g) ^ (ra & 7);
                    a[f] = *reinterpret_cast<const s16x8*>(&As[ra * BK + pa * 8]);
                    const int rb = wc * 64 + f * 16 + ln;
                    const int pb = (ks * 4 + g) ^ (rb & 7);
                    b[f] = *reinterpret_cast<const s16x8*>(&Bs[rb * BK + pb * 8]);
                }
                #pragma unroll
                for (int fi = 0; fi < 4; ++fi)
                    #pragma unroll
                    for (int fj = 0; fj < 4; ++fj)
                        acc[fi][fj] = __builtin_amdgcn_mfma_f32_16x16x32_bf16(
                            a[fi], b[fj], acc[fi][fj], 0, 0, 0);
            }
            __syncthreads();
        }

        // Epilogue: exp + masks. C/D layout: col = lane&15, row = (lane>>4)*4+reg.
        int li[16], si[16];
        #pragma unroll
        for (int t = 0; t < 16; ++t) {
            const int gi = i0 + wr * 64 + (t >> 2) * 16 + g * 4 + (t & 3);
            li[t] = lab[gi];
            si[t] = spk[gi];
        }
        #pragma unroll
        for (int fj = 0; fj < 4; ++fj) {
            const int gj  = j0 + wc * 64 + fj * 16 + ln;
            const int ljv = lab[gj];
            const int sjv = spk[gj];
            #pragma unroll
            for (int fi = 0; fi < 4; ++fi) {
                const int rbase = i0 + wr * 64 + fi * 16 + g * 4;
                #pragma unroll
                for (int reg = 0; reg < 4; ++reg) {
                    const int gi = rbase + reg;
                    const float e = __expf(acc[fi][fj][reg] * INV_TEMP);
                    const bool sl = (li[fi * 4 + reg] == ljv) && (gi != gj);
                    const bool sp = (si[fi * 4 + reg] == sjv);
                    nacc[fi * 4 + reg] += (sl && sp)  ? e : 0.0f;
                    dacc[fi * 4 + reg] += (sl && !sp) ? e : 0.0f;
                }
            }
        }
    }

    // Cross-lane reduce over the 16 column-lanes (same g group), then atomics.
    #pragma unroll
    for (int t = 0; t < 16; ++t) {
        float nv = nacc[t], dv = dacc[t];
        #pragma unroll
        for (int m = 1; m < 16; m <<= 1) {
            nv += __shfl_xor(nv, m);
            dv += __shfl_xor(dv, m);
        }
        if (ln == 0) {
            const int gi = i0 + wr * 64 + (t >> 2) * 16 + g * 4 + (t & 3);
            atomicAdd(&num[gi], nv);
            atomicAdd(&den[gi], dv);
        }
    }
}

__global__ void final_kernel(const float* __restrict__ num,
                             const float* __restrict__ den,
                             float* __restrict__ out) {
    __shared__ float s_tot[256];
    __shared__ int   s_cnt[256];
    float tot = 0.0f;
    int   cnt = 0;
    for (int i = threadIdx.x; i < NROWS; i += 256) {
        const float n = num[i];
        if (n > 0.0f) {               // valid <=> some positive exists (exp > 0)
            const float d = den[i] + n + EPS_V;
            tot += logf(d) - logf(n);
            cnt += 1;
        }
    }
    s_tot[threadIdx.x] = tot;
    s_cnt[threadIdx.x] = cnt;
    __syncthreads();
    for (int s = 128; s > 0; s >>= 1) {
        if (threadIdx.x < s) {
            s_tot[threadIdx.x] += s_tot[threadIdx.x + s];
            s_cnt[threadIdx.x] += s_cnt[threadIdx.x + s];
        }
        __syncthreads();
    }
    if (threadIdx.x == 0)
        out[0] = (s_cnt[0] > 0) ? (s_tot[0] / (float)s_cnt[0]) : 0.0f;
}

extern "C" void kernel_launch(void* const* d_in, const int* in_sizes, int n_in,
                              void* d_out, int out_size, void* d_ws, size_t ws_size,
                              hipStream_t stream) {
    const float* feat = (const float*)d_in[0];
    const int*   lab  = (const int*)d_in[1];
    const int*   spk  = (const int*)d_in[2];

    ushort* fbf = (ushort*)d_ws;
    float*  nd  = (float*)((char*)d_ws + (size_t)NROWS * DDIM * sizeof(ushort));
    float*  num = nd;
    float*  den = nd + NROWS;
    float*  out = (float*)d_out;

    zero_kernel<<<(2 * NROWS + 255) / 256, 256, 0, stream>>>(nd);
    normbf_kernel<<<(NROWS * 64) / 256, 256, 0, stream>>>(feat, fbf);
    dim3 grid(NROWS / BI, JSPLIT);
    main_kernel<<<grid, 256, 0, stream>>>(fbf, lab, spk, num, den);
    final_kernel<<<1, 256, 0, stream>>>(num, den, out);
}

// Round 3
// 175.623 us; speedup vs baseline: 7.5295x; 1.1430x over previous
//
#include <hip/hip_runtime.h>
#include <math.h>

// Problem constants (fixed by reference setup_inputs)
#define NROWS 8192
#define DDIM  256
#define INV_TEMP 1.25f      // 1/0.8
#define EPS_V 1e-7f

// Tiling: symmetric tile-pair enumeration, 128x128 tiles, BK=64 double-buffered
#define BT 128
#define BK 64
#define NTILE (NROWS / BT)              // 64
#define NBLK  (NTILE * (NTILE + 1) / 2) // 2080 blocks, ti >= tj

typedef float f32x4 __attribute__((ext_vector_type(4)));
typedef short s16x8 __attribute__((ext_vector_type(8)));

// ---------------- workspace layout ----------------
// [0    .. 4MB )   fbf  : normalized features bf16 (ushort), row-major 8192x256
// [4MB  .. +32KB)  num  : 8192 f32
// [+32K .. +64KB)  den  : 8192 f32
// [+64K .. +96KB)  keys : 8192 i32, key = (spk<<3)|lab  (spk<64, lab<8)

__device__ __forceinline__ ushort f2bf(float x) {
    unsigned u = __float_as_uint(x);
    unsigned r = (u + 0x7FFFu + ((u >> 16) & 1u)) >> 16;   // RNE
    return (ushort)r;
}

// async global->LDS, 16B per lane. LDS dest = wave-uniform base + lane*16 (linear).
// CK-style addrspace cast via uintptr_t (generic LDS ptr low 32 bits = LDS offset).
__device__ __forceinline__ void gload16(const void* gptr, void* lptr) {
    __builtin_amdgcn_global_load_lds(
        (__attribute__((address_space(1))) void*)(uintptr_t)gptr,
        (__attribute__((address_space(3))) void*)(uintptr_t)lptr,
        16, 0, 0);
}

// One wave per row: normalize, convert to bf16, emit packed mask key.
// Also zero-initializes num/den (first 16384 threads).
__global__ void normbf_kernel(const float* __restrict__ feat,
                              const int*   __restrict__ lab,
                              const int*   __restrict__ spk,
                              ushort* __restrict__ fbf,
                              float*  __restrict__ nd,
                              int*    __restrict__ keys) {
    const int gt = blockIdx.x * blockDim.x + threadIdx.x;
    if (gt < 2 * NROWS) nd[gt] = 0.0f;
    const int row  = gt >> 6;
    const int lane = gt & 63;
    const float4 v = reinterpret_cast<const float4*>(feat + (size_t)row * DDIM)[lane];
    float ss = v.x * v.x + v.y * v.y + v.z * v.z + v.w * v.w;
    #pragma unroll
    for (int m = 32; m; m >>= 1) ss += __shfl_xor(ss, m);
    const float inv = 1.0f / fmaxf(sqrtf(ss), 1e-12f);
    ushort4 o;
    o.x = f2bf(v.x * inv);
    o.y = f2bf(v.y * inv);
    o.z = f2bf(v.z * inv);
    o.w = f2bf(v.w * inv);
    reinterpret_cast<ushort4*>(fbf + (size_t)row * DDIM)[lane] = o;
    if (lane == 0) keys[row] = (spk[row] << 3) | lab[row];
}

// One block per tile-pair (ti >= tj). 4 waves in 2x2, each owns a 64x64 quadrant.
// global_load_lds staging (linear LDS dest, inverse-swizzled global source),
// XOR-swizzled ds_read (chunk ^ (row&7)), 2-phase prefetch, fused exp+mask
// epilogue with BOTH row-side (rows of I) and col-side (rows of J) reductions.
__global__ __launch_bounds__(256) void main_kernel(
        const ushort* __restrict__ fbf,
        const int*    __restrict__ keys,
        float*        __restrict__ num,
        float*        __restrict__ den) {
    __shared__ __align__(16) ushort Asm[2][BT * BK];   // 32 KB
    __shared__ __align__(16) ushort Bsm[2][BT * BK];   // 32 KB

    const int tid  = threadIdx.x;
    const int lane = tid & 63;
    const int wid  = tid >> 6;
    const int wr   = wid >> 1;
    const int wc   = wid & 1;
    const int g    = lane >> 4;
    const int ln   = lane & 15;

    // Triangular decode: block b -> (ti, tj), tj <= ti
    const int b = blockIdx.x;
    int ti = (int)((sqrtf(8.0f * (float)b + 1.0f) - 1.0f) * 0.5f);
    while ((ti + 1) * (ti + 2) / 2 <= b) ++ti;
    while (ti * (ti + 1) / 2 > b) --ti;
    const int tj = b - ti * (ti + 1) / 2;
    const int i0 = ti * BT;
    const int j0 = tj * BT;
    const bool isdiag = (ti == tj);

    // Staging lane constants: lane covers phys slot (row = r0+(l>>3), chunk = l&7);
    // it must fetch logical chunk (l&7)^(row&7); r0 % 8 == 0 so row&7 == l>>3.
    const int rsub = lane >> 3;
    const int clog = (lane & 7) ^ rsub;

    f32x4 acc[4][4];
    #pragma unroll
    for (int fi = 0; fi < 4; ++fi)
        #pragma unroll
        for (int fj = 0; fj < 4; ++fj)
            #pragma unroll
            for (int k = 0; k < 4; ++k) acc[fi][fj][k] = 0.0f;

    // ---- prologue stage ----
    {
        #pragma unroll
        for (int q = 0; q < 4; ++q) {
            const int r0  = wid * 32 + q * 8;
            const int row = r0 + rsub;
            gload16(fbf + (size_t)(i0 + row) * DDIM + 0 + clog * 8, &Asm[0][r0 * BK]);
            gload16(fbf + (size_t)(j0 + row) * DDIM + 0 + clog * 8, &Bsm[0][r0 * BK]);
        }
    }
    __syncthreads();

    for (int kc = 0; kc < DDIM / BK; ++kc) {
        if (kc < DDIM / BK - 1) {
            const int nb = (kc + 1) & 1;
            const int ko = (kc + 1) * BK;
            #pragma unroll
            for (int q = 0; q < 4; ++q) {
                const int r0  = wid * 32 + q * 8;
                const int row = r0 + rsub;
                gload16(fbf + (size_t)(i0 + row) * DDIM + ko + clog * 8, &Asm[nb][r0 * BK]);
                gload16(fbf + (size_t)(j0 + row) * DDIM + ko + clog * 8, &Bsm[nb][r0 * BK]);
            }
        }
        const ushort* A = Asm[kc & 1];
        const ushort* B = Bsm[kc & 1];
        #pragma unroll
        for (int ks = 0; ks < 2; ++ks) {
            s16x8 a[4], bb[4];
            const int pch = ((ks * 4 + g) ^ (ln & 7)) * 8;   // row&7 == ln&7 here
            #pragma unroll
            for (int f = 0; f < 4; ++f) {
                a[f]  = *reinterpret_cast<const s16x8*>(&A[(wr * 64 + f * 16 + ln) * BK + pch]);
                bb[f] = *reinterpret_cast<const s16x8*>(&B[(wc * 64 + f * 16 + ln) * BK + pch]);
            }
            #pragma unroll
            for (int fi = 0; fi < 4; ++fi)
                #pragma unroll
                for (int fj = 0; fj < 4; ++fj)
                    acc[fi][fj] = __builtin_amdgcn_mfma_f32_16x16x32_bf16(
                        a[fi], bb[fj], acc[fi][fj], 0, 0, 0);
        }
        __syncthreads();   // drains vmcnt (stage of next buffer) + protects WAR
    }

    // ---- epilogue: exp + mask + dual-axis accumulation ----
    // C/D layout: col = lane&15, row = (lane>>4)*4 + reg.
    float nacc[16], dacc[16], cn[4], cd[4];
    #pragma unroll
    for (int t = 0; t < 16; ++t) { nacc[t] = 0.0f; dacc[t] = 0.0f; }
    #pragma unroll
    for (int t = 0; t < 4; ++t) { cn[t] = 0.0f; cd[t] = 0.0f; }

    int ki[16];
    #pragma unroll
    for (int t = 0; t < 16; ++t)
        ki[t] = keys[i0 + wr * 64 + (t >> 2) * 16 + g * 4 + (t & 3)];

    #pragma unroll
    for (int fj = 0; fj < 4; ++fj) {
        const int gj = j0 + wc * 64 + fj * 16 + ln;
        const int kj = keys[gj];
        #pragma unroll
        for (int fi = 0; fi < 4; ++fi) {
            #pragma unroll
            for (int r = 0; r < 4; ++r) {
                const int t  = fi * 4 + r;
                const int gi = i0 + wr * 64 + fi * 16 + g * 4 + r;
                const float e = __expf(acc[fi][fj][r] * INV_TEMP);
                const bool pos = (ki[t] == kj) && (gi != gj);            // same lab+spk, not self
                const bool neg = (((ki[t] ^ kj) & 7) == 0) && (ki[t] != kj); // same lab, diff spk
                const float pe = pos ? e : 0.0f;
                const float ne = neg ? e : 0.0f;
                nacc[t] += pe;
                dacc[t] += ne;
                cn[fj]  += pe;
                cd[fj]  += ne;
            }
        }
    }

    // Row-side: reduce over the 16 column-lanes (within g-group), atomics at ln==0.
    #pragma unroll
    for (int t = 0; t < 16; ++t) {
        float nv = nacc[t], dv = dacc[t];
        #pragma unroll
        for (int m = 1; m < 16; m <<= 1) {
            nv += __shfl_xor(nv, m);
            dv += __shfl_xor(dv, m);
        }
        if (ln == 0) {
            const int gi = i0 + wr * 64 + (t >> 2) * 16 + g * 4 + (t & 3);
            atomicAdd(&num[gi], nv);
            atomicAdd(&den[gi], dv);
        }
    }
    // Col-side (mirror contribution of the transposed tile); skip on diagonal.
    if (!isdiag) {
        #pragma unroll
        for (int fj = 0; fj < 4; ++fj) {
            float nv = cn[fj], dv = cd[fj];
            nv += __shfl_xor(nv, 16); dv += __shfl_xor(dv, 16);
            nv += __shfl_xor(nv, 32); dv += __shfl_xor(dv, 32);
            if (g == 0) {
                const int gj = j0 + wc * 64 + fj * 16 + ln;
                atomicAdd(&num[gj], nv);
                atomicAdd(&den[gj], dv);
            }
        }
    }
}

__global__ void final_kernel(const float* __restrict__ num,
                             const float* __restrict__ den,
                             float* __restrict__ out) {
    __shared__ float s_tot[256];
    __shared__ int   s_cnt[256];
    float tot = 0.0f;
    int   cnt = 0;
    for (int i = threadIdx.x; i < NROWS; i += 256) {
        const float n = num[i];
        if (n > 0.0f) {               // valid <=> some positive exists (exp > 0)
            const float d = den[i] + n + EPS_V;
            tot += logf(d) - logf(n);
            cnt += 1;
        }
    }
    s_tot[threadIdx.x] = tot;
    s_cnt[threadIdx.x] = cnt;
    __syncthreads();
    for (int s = 128; s > 0; s >>= 1) {
        if (threadIdx.x < s) {
            s_tot[threadIdx.x] += s_tot[threadIdx.x + s];
            s_cnt[threadIdx.x] += s_cnt[threadIdx.x + s];
        }
        __syncthreads();
    }
    if (threadIdx.x == 0)
        out[0] = (s_cnt[0] > 0) ? (s_tot[0] / (float)s_cnt[0]) : 0.0f;
}

extern "C" void kernel_launch(void* const* d_in, const int* in_sizes, int n_in,
                              void* d_out, int out_size, void* d_ws, size_t ws_size,
                              hipStream_t stream) {
    const float* feat = (const float*)d_in[0];
    const int*   lab  = (const int*)d_in[1];
    const int*   spk  = (const int*)d_in[2];

    ushort* fbf  = (ushort*)d_ws;
    float*  nd   = (float*)((char*)d_ws + (size_t)NROWS * DDIM * sizeof(ushort));
    float*  num  = nd;
    float*  den  = nd + NROWS;
    int*    keys = (int*)(nd + 2 * NROWS);
    float*  out  = (float*)d_out;

    normbf_kernel<<<(NROWS * 64) / 256, 256, 0, stream>>>(feat, lab, spk, fbf, nd, keys);
    main_kernel<<<NBLK, 256, 0, stream>>>(fbf, keys, num, den);
    final_kernel<<<1, 256, 0, stream>>>(num, den, out);
}

// Round 4
// 135.948 us; speedup vs baseline: 9.7268x; 1.2918x over previous
//
#include <hip/hip_runtime.h>
#include <math.h>

// Problem constants (fixed by reference setup_inputs)
#define NROWS 8192
#define DDIM  256
#define EPS_V 1e-7f

// Structure: 64 panels (128 rows) x 4 j-chunks (2048 cols) = 256 blocks = 1/CU.
// Block = 8 waves (512 thr). Wave owns 64 rows x 16 cols: fi=4 (16-row frags),
// A panel in registers (4x8 s16x8), B j-tile (64x256) LDS double-buffered.
#define JCHUNK 2048
#define NJT    (JCHUNK / 64)    // 32 j-tiles per block

typedef float f32x4 __attribute__((ext_vector_type(4)));
typedef short s16x8 __attribute__((ext_vector_type(8)));

// ---------------- workspace layout ----------------
// [0    .. 4MB )   fbf  : normalized features bf16 (ushort), row-major 8192x256
// [4MB  .. +32KB)  num  : 8192 f32  (P = sum of positives)
// [+32K .. +64KB)  den  : 8192 f32  (T = sum over same-label (incl pos), ~eye)
// [+64K .. +96KB)  keys : 8192 i32, key = (spk<<3)|lab

__device__ __forceinline__ ushort f2bf(float x) {
    unsigned u = __float_as_uint(x);
    unsigned r = (u + 0x7FFFu + ((u >> 16) & 1u)) >> 16;   // RNE
    return (ushort)r;
}

// async global->LDS, 16B/lane; LDS dest is wave-uniform base (+lane*16 implicit).
__device__ __forceinline__ void gload16(const void* gptr, void* lptr) {
    __builtin_amdgcn_global_load_lds(
        (__attribute__((address_space(1))) void*)(uintptr_t)gptr,
        (__attribute__((address_space(3))) void*)(uintptr_t)lptr,
        16, 0, 0);
}

// One wave per row: normalize, convert to bf16, emit packed key; zero num/den.
__global__ void normbf_kernel(const float* __restrict__ feat,
                              const int*   __restrict__ lab,
                              const int*   __restrict__ spk,
                              ushort* __restrict__ fbf,
                              float*  __restrict__ nd,
                              int*    __restrict__ keys) {
    const int gt = blockIdx.x * blockDim.x + threadIdx.x;
    if (gt < 2 * NROWS) nd[gt] = 0.0f;
    const int row  = gt >> 6;
    const int lane = gt & 63;
    const float4 v = reinterpret_cast<const float4*>(feat + (size_t)row * DDIM)[lane];
    float ss = v.x * v.x + v.y * v.y + v.z * v.z + v.w * v.w;
    #pragma unroll
    for (int m = 32; m; m >>= 1) ss += __shfl_xor(ss, m);
    const float inv = 1.0f / fmaxf(sqrtf(ss), 1e-12f);
    ushort4 o;
    o.x = f2bf(v.x * inv);
    o.y = f2bf(v.y * inv);
    o.z = f2bf(v.z * inv);
    o.w = f2bf(v.w * inv);
    reinterpret_cast<ushort4*>(fbf + (size_t)row * DDIM)[lane] = o;
    if (lane == 0) keys[row] = (spk[row] << 3) | lab[row];
}

__global__ __launch_bounds__(512, 2) void main_kernel(
        const ushort* __restrict__ fbf,
        const int*    __restrict__ keys,
        float*        __restrict__ num,
        float*        __restrict__ den) {
    __shared__ __align__(16) ushort As[128 * DDIM];      // 64 KB, staged once
    __shared__ __align__(16) ushort Bs[2][64 * DDIM];    // 2 x 32 KB dbuf

    const int tid  = threadIdx.x;
    const int lane = tid & 63;
    const int wid  = tid >> 6;      // 0..7
    const int wr   = wid >> 2;      // 0..1  (64-row half of panel)
    const int wc   = wid & 3;       // 0..3  (16-col stripe of j-tile)
    const int g    = lane >> 4;     // 0..3
    const int ln   = lane & 15;

    const int panel = blockIdx.x & 63;
    const int jc    = blockIdx.x >> 6;
    const int p0    = panel * 128;
    const int jbase = jc * JCHUNK;

    // staging lane decomposition: lane covers (rsub = lane>>5, phys chunk = lane&31);
    // logical chunk = phys ^ (row&7)  (involution; same XOR applied on reads)
    const int rsub  = lane >> 5;
    const int cphys = lane & 31;

    // ---- prologue: stage A panel (128 rows) + B[0] (64 rows) ----
    #pragma unroll
    for (int q = 0; q < 8; ++q) {
        const int r0  = wid * 16 + q * 2;
        const int row = r0 + rsub;
        const int cl  = cphys ^ (row & 7);
        gload16(fbf + (size_t)(p0 + row) * DDIM + cl * 8, &As[r0 * DDIM]);
    }
    #pragma unroll
    for (int q = 0; q < 4; ++q) {
        const int r0  = wid * 8 + q * 2;
        const int row = r0 + rsub;
        const int cl  = cphys ^ (row & 7);
        gload16(fbf + (size_t)(jbase + row) * DDIM + cl * 8, &Bs[0][r0 * DDIM]);
    }
    __syncthreads();

    // A fragments into registers: wave's 64 rows x full K. row&7 == ln&7.
    s16x8 a[4][8];
    #pragma unroll
    for (int fi = 0; fi < 4; ++fi) {
        const int row = wr * 64 + fi * 16 + ln;
        #pragma unroll
        for (int kf = 0; kf < 8; ++kf) {
            const int ch = (kf * 4 + g) ^ (ln & 7);
            a[fi][kf] = *reinterpret_cast<const s16x8*>(&As[row * DDIM + ch * 8]);
        }
    }
    int ki[16];
    #pragma unroll
    for (int t = 0; t < 16; ++t)
        ki[t] = keys[p0 + wr * 64 + (t >> 2) * 16 + g * 4 + (t & 3)];

    float T[16], P[16];
    #pragma unroll
    for (int t = 0; t < 16; ++t) { T[t] = 0.0f; P[t] = 0.0f; }

    // diagonal lives in this block iff panel's rows fall in this j-chunk
    const int diag_jt0 = ((p0 >> 11) == jc) ? ((p0 & 2047) >> 6) : -3;

    for (int jt = 0; jt < NJT; ++jt) {
        const int cur = jt & 1;
        // stage next j-tile early: ~32 MFMA + epilogue before the drain barrier
        if (jt + 1 < NJT) {
            const int j0n = jbase + (jt + 1) * 64;
            #pragma unroll
            for (int q = 0; q < 4; ++q) {
                const int r0  = wid * 8 + q * 2;
                const int row = r0 + rsub;
                const int cl  = cphys ^ (row & 7);
                gload16(fbf + (size_t)(j0n + row) * DDIM + cl * 8, &Bs[cur ^ 1][r0 * DDIM]);
            }
        }
        const int j0 = jbase + jt * 64;
        const int gj = j0 + wc * 16 + ln;
        const int kj = keys[gj];                  // issued early, used ~1k cyc later

        f32x4 acc[4];
        #pragma unroll
        for (int fi = 0; fi < 4; ++fi)
            #pragma unroll
            for (int k = 0; k < 4; ++k) acc[fi][k] = 0.0f;

        #pragma unroll
        for (int kf = 0; kf < 8; ++kf) {
            const int ch = (kf * 4 + g) ^ (ln & 7);
            const s16x8 b = *reinterpret_cast<const s16x8*>(
                &Bs[cur][(wc * 16 + ln) * DDIM + ch * 8]);
            #pragma unroll
            for (int fi = 0; fi < 4; ++fi)
                acc[fi] = __builtin_amdgcn_mfma_f32_16x16x32_bf16(a[fi][kf], b, acc[fi], 0, 0, 0);
        }

        // epilogue: C/D layout col = lane&15 (== ln), row = g*4 + reg (+fi*16+wr*64)
        if (jt == diag_jt0 || jt == diag_jt0 + 1) {
            #pragma unroll
            for (int fi = 0; fi < 4; ++fi)
                #pragma unroll
                for (int r = 0; r < 4; ++r) {
                    const int t  = fi * 4 + r;
                    const int gi = p0 + wr * 64 + fi * 16 + g * 4 + r;
                    const float e = __expf(acc[fi][r] * 1.25f);
                    const int  kd = ki[t] ^ kj;
                    const bool ns = (gi != gj);
                    T[t] += (((kd & 7) == 0) && ns) ? e : 0.0f;
                    P[t] += ((kd == 0) && ns) ? e : 0.0f;
                }
        } else {
            #pragma unroll
            for (int fi = 0; fi < 4; ++fi)
                #pragma unroll
                for (int r = 0; r < 4; ++r) {
                    const int t = fi * 4 + r;
                    const float e = __expf(acc[fi][r] * 1.25f);
                    const int  kd = ki[t] ^ kj;
                    T[t] += ((kd & 7) == 0) ? e : 0.0f;
                    P[t] += (kd == 0) ? e : 0.0f;
                }
        }
        __syncthreads();   // drains stage of jt+1; WAR-protects Bs[cur] for jt+2
    }

    // Reduce over the 16 column-lanes, then 1 atomic per (row, wave, array).
    #pragma unroll
    for (int t = 0; t < 16; ++t) {
        float pv = P[t], tv = T[t];
        #pragma unroll
        for (int m = 1; m < 16; m <<= 1) {
            pv += __shfl_xor(pv, m);
            tv += __shfl_xor(tv, m);
        }
        if (ln == 0) {
            const int gi = p0 + wr * 64 + (t >> 2) * 16 + g * 4 + (t & 3);
            atomicAdd(&num[gi], pv);
            atomicAdd(&den[gi], tv);
        }
    }
}

__global__ void final_kernel(const float* __restrict__ num,
                             const float* __restrict__ den,
                             float* __restrict__ out) {
    __shared__ float s_tot[1024];
    __shared__ int   s_cnt[1024];
    float tot = 0.0f;
    int   cnt = 0;
    for (int i = threadIdx.x; i < NROWS; i += 1024) {
        const float n = num[i];
        if (n > 0.0f) {                       // valid <=> some positive exists
            const float d = den[i] + EPS_V;   // den slot holds T = num + negatives
            tot += logf(d) - logf(n);
            cnt += 1;
        }
    }
    s_tot[threadIdx.x] = tot;
    s_cnt[threadIdx.x] = cnt;
    __syncthreads();
    for (int s = 512; s > 0; s >>= 1) {
        if (threadIdx.x < s) {
            s_tot[threadIdx.x] += s_tot[threadIdx.x + s];
            s_cnt[threadIdx.x] += s_cnt[threadIdx.x + s];
        }
        __syncthreads();
    }
    if (threadIdx.x == 0)
        out[0] = (s_cnt[0] > 0) ? (s_tot[0] / (float)s_cnt[0]) : 0.0f;
}

extern "C" void kernel_launch(void* const* d_in, const int* in_sizes, int n_in,
                              void* d_out, int out_size, void* d_ws, size_t ws_size,
                              hipStream_t stream) {
    const float* feat = (const float*)d_in[0];
    const int*   lab  = (const int*)d_in[1];
    const int*   spk  = (const int*)d_in[2];

    ushort* fbf  = (ushort*)d_ws;
    float*  nd   = (float*)((char*)d_ws + (size_t)NROWS * DDIM * sizeof(ushort));
    float*  num  = nd;
    float*  den  = nd + NROWS;
    int*    keys = (int*)(nd + 2 * NROWS);
    float*  out  = (float*)d_out;

    normbf_kernel<<<(NROWS * 64) / 256, 256, 0, stream>>>(feat, lab, spk, fbf, nd, keys);
    main_kernel<<<256, 512, 0, stream>>>(fbf, keys, num, den);
    final_kernel<<<1, 1024, 0, stream>>>(num, den, out);
}